// Round 1
// baseline (29152.878 us; speedup 1.0000x reference)
//
#include <hip/hip_runtime.h>
#include <math.h>

// Decoder: B=1024, Z=256, TDIM=512, CF=1024, A=64, R=128, T=64
// Strategy (round 0, fp32 correctness baseline):
//  - t_rec and base_* = t_rec@Wih[:, :512].T + b precomputed once (t_rec constant over T)
//  - one-hot matmul contributions = column gathers from pre-transposed E tables
//  - per step: 3 fp32 GEMMs h@Whh.T (fused rt pair via gridDim.z), pointwise LSTM,
//    K-split head GEMMs + wave-level softmax/argmax reduce kernels.

__device__ __forceinline__ float sigf(float x) { return 1.0f / (1.0f + expf(-x)); }

// ---------------- main fp32 GEMM: C = A[M,K] @ W[N,K]^T (+bias)(+relu) ----------------
// tiles: BM=128, BN=64, BK=16, 256 threads, micro 4x8
__global__ __launch_bounds__(256) void gemm_f32(
    const float* __restrict__ A0, const float* __restrict__ W0, float* __restrict__ C0,
    const float* __restrict__ A1, const float* __restrict__ W1, float* __restrict__ C1,
    int lda, int ldw, int ldc, int K, const float* __restrict__ bias, int relu)
{
    const float* Ap = blockIdx.z ? A1 : A0;
    const float* Wp = blockIdx.z ? W1 : W0;
    float*       Cp = blockIdx.z ? C1 : C0;
    __shared__ float As[16][128];
    __shared__ float Bs[16][64];
    const int tid = threadIdx.x;
    const int m0 = blockIdx.x * 128, n0 = blockIdx.y * 64;
    const int tx = tid & 7, ty = tid >> 3;
    const bool wal = (ldw & 3) == 0;
    float acc[4][8];
#pragma unroll
    for (int i = 0; i < 4; i++)
#pragma unroll
        for (int j = 0; j < 8; j++) acc[i][j] = 0.0f;

    for (int k0 = 0; k0 < K; k0 += 16) {
        __syncthreads();
#pragma unroll
        for (int q = 0; q < 2; q++) {
            int t2 = tid + q * 256;
            int kq = t2 & 3, m = t2 >> 2;
            float4 v = *(const float4*)(Ap + (size_t)(m0 + m) * lda + k0 + kq * 4);
            As[kq * 4 + 0][m] = v.x; As[kq * 4 + 1][m] = v.y;
            As[kq * 4 + 2][m] = v.z; As[kq * 4 + 3][m] = v.w;
        }
        {
            int kq = tid & 3, n = tid >> 2;
            const float* src = Wp + (size_t)(n0 + n) * ldw + k0 + kq * 4;
            float4 v;
            if (wal) v = *(const float4*)src;
            else { v.x = src[0]; v.y = src[1]; v.z = src[2]; v.w = src[3]; }
            Bs[kq * 4 + 0][n] = v.x; Bs[kq * 4 + 1][n] = v.y;
            Bs[kq * 4 + 2][n] = v.z; Bs[kq * 4 + 3][n] = v.w;
        }
        __syncthreads();
#pragma unroll
        for (int k = 0; k < 16; k++) {
            float a4[4], b8[8];
            *(float4*)a4 = *(const float4*)&As[k][ty * 4];
            *(float4*)(b8) = *(const float4*)&Bs[k][tx * 8];
            *(float4*)(b8 + 4) = *(const float4*)&Bs[k][tx * 8 + 4];
#pragma unroll
            for (int i = 0; i < 4; i++)
#pragma unroll
                for (int j = 0; j < 8; j++) acc[i][j] = fmaf(a4[i], b8[j], acc[i][j]);
        }
    }
#pragma unroll
    for (int i = 0; i < 4; i++) {
        int m = m0 + ty * 4 + i;
        float vb[8];
#pragma unroll
        for (int j = 0; j < 8; j++) {
            float v = acc[i][j];
            if (bias) v += bias[n0 + tx * 8 + j];
            if (relu) v = fmaxf(v, 0.0f);
            vb[j] = v;
        }
        float* dst = Cp + (size_t)m * ldc + n0 + tx * 8;
        *(float4*)dst = make_float4(vb[0], vb[1], vb[2], vb[3]);
        *(float4*)(dst + 4) = make_float4(vb[4], vb[5], vb[6], vb[7]);
    }
}

// ------------- K-split small-N GEMM: part[kc][m][n] = sum_{k in chunk} A[m,k] W[n,k] -------------
// BM=64, BK=32, 256 threads. grid (M/64, N/BN, KC)
template <int BN, int TM, int TN>
__global__ __launch_bounds__(256) void head_partial(
    const float* __restrict__ A, int lda,
    const float* __restrict__ W, int ldw,
    float* __restrict__ part, int N, int Kchunk)
{
    __shared__ float As[32][64];
    __shared__ float Bs[32][BN];
    const int tid = threadIdx.x;
    const int m0 = blockIdx.x * 64, n0 = blockIdx.y * BN;
    const int kc = blockIdx.z;
    constexpr int TX = BN / TN;
    const int tx = tid % TX, ty = tid / TX;
    float acc[TM][TN];
#pragma unroll
    for (int i = 0; i < TM; i++)
#pragma unroll
        for (int j = 0; j < TN; j++) acc[i][j] = 0.0f;

    const int kb = kc * Kchunk;
    for (int k0 = kb; k0 < kb + Kchunk; k0 += 32) {
        __syncthreads();
#pragma unroll
        for (int q = 0; q < 2; q++) {
            int t2 = tid + q * 256;
            int kq = t2 & 7, m = t2 >> 3;
            float4 v = *(const float4*)(A + (size_t)(m0 + m) * lda + k0 + kq * 4);
            As[kq * 4 + 0][m] = v.x; As[kq * 4 + 1][m] = v.y;
            As[kq * 4 + 2][m] = v.z; As[kq * 4 + 3][m] = v.w;
        }
#pragma unroll
        for (int q = 0; q < BN / 32; q++) {
            int t2 = tid + q * 256;
            int kq = t2 & 7, n = t2 >> 3;
            float4 v = *(const float4*)(W + (size_t)(n0 + n) * ldw + k0 + kq * 4);
            Bs[kq * 4 + 0][n] = v.x; Bs[kq * 4 + 1][n] = v.y;
            Bs[kq * 4 + 2][n] = v.z; Bs[kq * 4 + 3][n] = v.w;
        }
        __syncthreads();
#pragma unroll
        for (int k = 0; k < 32; k++) {
            float av[TM], bv[TN];
#pragma unroll
            for (int i = 0; i < TM; i++) av[i] = As[k][ty * TM + i];
#pragma unroll
            for (int j = 0; j < TN; j++) bv[j] = Bs[k][tx * TN + j];
#pragma unroll
            for (int i = 0; i < TM; i++)
#pragma unroll
                for (int j = 0; j < TN; j++) acc[i][j] = fmaf(av[i], bv[j], acc[i][j]);
        }
    }
#pragma unroll
    for (int i = 0; i < TM; i++) {
        int m = m0 + ty * TM + i;
        float* dst = part + ((size_t)kc * 1024 + m) * N + n0 + tx * TN;
#pragma unroll
        for (int j = 0; j < TN; j += 4)
            *(float4*)(dst + j) = make_float4(acc[i][j], acc[i][j + 1], acc[i][j + 2], acc[i][j + 3]);
    }
}

// ------------- pointwise LSTM: gates = G + base + E1[idx1] (+E2[idx2]) (+tsv*wcol) -------------
__global__ __launch_bounds__(256) void lstm_pw(
    const float* __restrict__ gates, const float* __restrict__ base,
    const float* __restrict__ E1, const int* __restrict__ idx1,
    const float* __restrict__ E2, const int* __restrict__ idx2,
    const float* __restrict__ wcol, const float* __restrict__ tsv,
    float* __restrict__ h, float* __restrict__ c)
{
    int i = blockIdx.x * 256 + threadIdx.x;   // over B*CF = 1M
    int b = i >> 10, j = i & 1023;
    size_t r = (size_t)b * 4096 + j;
    const float* e1 = E1 + (size_t)idx1[b] * 4096 + j;
    float gi = gates[r]        + base[r]        + e1[0];
    float gf = gates[r + 1024] + base[r + 1024] + e1[1024];
    float gg = gates[r + 2048] + base[r + 2048] + e1[2048];
    float go = gates[r + 3072] + base[r + 3072] + e1[3072];
    if (E2) {
        const float* e2 = E2 + (size_t)idx2[b] * 4096 + j;
        gi += e2[0]; gf += e2[1024]; gg += e2[2048]; go += e2[3072];
    }
    if (wcol) {
        float tv = tsv[b];
        gi = fmaf(tv, wcol[j], gi);        gf = fmaf(tv, wcol[j + 1024], gf);
        gg = fmaf(tv, wcol[j + 2048], gg); go = fmaf(tv, wcol[j + 3072], go);
    }
    float cn = sigf(gf) * c[i] + sigf(gi) * tanhf(gg);
    c[i] = cn;
    h[i] = sigf(go) * tanhf(cn);
}

// ------------- act head reduce: logits -> softmax -> out, argmax -> aidx -------------
__global__ __launch_bounds__(256) void act_reduce(
    const float* __restrict__ part, const float* __restrict__ bias,
    float* __restrict__ out_probs, int t, int* __restrict__ aidx)
{
    int lane = threadIdx.x & 63;
    int b = blockIdx.x * 4 + (threadIdx.x >> 6);
    float l = bias[lane];
#pragma unroll
    for (int kc = 0; kc < 8; kc++) l += part[((size_t)kc * 1024 + b) * 64 + lane];
    float v = l; int idx = lane;
#pragma unroll
    for (int off = 32; off; off >>= 1) {
        float ov = __shfl_xor(v, off);
        int   oi = __shfl_xor(idx, off);
        if (ov > v || (ov == v && oi < idx)) { v = ov; idx = oi; }
    }
    float e = expf(l - v);
    float s = e;
#pragma unroll
    for (int off = 32; off; off >>= 1) s += __shfl_xor(s, off);
    out_probs[((size_t)b * 64 + t) * 64 + lane] = e / s;
    if (lane == 0) aidx[b] = idx;
}

__global__ __launch_bounds__(256) void res_reduce(
    const float* __restrict__ part, const float* __restrict__ bias,
    float* __restrict__ out_probs, int t, int* __restrict__ ridx)
{
    int lane = threadIdx.x & 63;
    int b = blockIdx.x * 4 + (threadIdx.x >> 6);
    float l0 = bias[lane], l1 = bias[lane + 64];
#pragma unroll
    for (int kc = 0; kc < 8; kc++) {
        const float* p = part + ((size_t)kc * 1024 + b) * 128;
        l0 += p[lane]; l1 += p[lane + 64];
    }
    float v = l0; int idx = lane;
    if (l1 > v) { v = l1; idx = lane + 64; }
#pragma unroll
    for (int off = 32; off; off >>= 1) {
        float ov = __shfl_xor(v, off);
        int   oi = __shfl_xor(idx, off);
        if (ov > v || (ov == v && oi < idx)) { v = ov; idx = oi; }
    }
    float e0 = expf(l0 - v), e1 = expf(l1 - v);
    float s = e0 + e1;
#pragma unroll
    for (int off = 32; off; off >>= 1) s += __shfl_xor(s, off);
    float* dst = out_probs + ((size_t)b * 64 + t) * 128;
    dst[lane] = e0 / s; dst[lane + 64] = e1 / s;
    if (lane == 0) ridx[b] = idx;
}

// ------------- ts head: u = relu(sum parts + b1); ts = u . w2 + b2 -------------
__global__ __launch_bounds__(256) void ts_u_kernel(
    const float* __restrict__ part, const float* __restrict__ b1, float* __restrict__ u)
{
    int i = blockIdx.x * 256 + threadIdx.x;   // over 1024*512
    float v = b1[i & 511] + part[i] + part[i + 524288] + part[i + 1048576] + part[i + 1572864];
    u[i] = fmaxf(v, 0.0f);
}

__global__ __launch_bounds__(256) void ts_final(
    const float* __restrict__ u, const float* __restrict__ w2, const float* __restrict__ b2,
    float* __restrict__ out_ts, int t, float* __restrict__ tsv)
{
    int lane = threadIdx.x & 63;
    int b = blockIdx.x * 4 + (threadIdx.x >> 6);
    const float* ur = u + (size_t)b * 512;
    float s = 0.0f;
#pragma unroll
    for (int q = 0; q < 8; q++) s = fmaf(ur[lane + q * 64], w2[lane + q * 64], s);
#pragma unroll
    for (int off = 32; off; off >>= 1) s += __shfl_xor(s, off);
    if (lane == 0) {
        float r = s + b2[0];
        out_ts[b * 64 + t] = r;
        tsv[b] = r;
    }
}

// ------------- setup kernels -------------
__global__ void extract_cols(const float* __restrict__ Wih, int ldw, int col0, int ncols,
                             float* __restrict__ E)
{
    int i = blockIdx.x * 256 + threadIdx.x;
    if (i >= ncols * 4096) return;
    int c = i % ncols, j = i / ncols;
    E[(size_t)c * 4096 + j] = Wih[(size_t)j * ldw + col0 + c];
}

__global__ void init_state(float* __restrict__ hc, float* __restrict__ tsv,
                           int* __restrict__ aidx, int* __restrict__ ridx, int n)
{
    int i = blockIdx.x * 256 + threadIdx.x;
    if (i < n) hc[i] = 0.0f;
    if (i < 1024) { tsv[i] = 0.0f; aidx[i] = 63; ridx[i] = 127; }
}

extern "C" void kernel_launch(void* const* d_in, const int* in_sizes, int n_in,
                              void* d_out, int out_size, void* d_ws, size_t ws_size,
                              hipStream_t stream)
{
    const float* z       = (const float*)d_in[0];
    const float* z2t_w   = (const float*)d_in[1];
    const float* z2t_b   = (const float*)d_in[2];
    const float* Wih_a   = (const float*)d_in[3];
    const float* Whh_a   = (const float*)d_in[4];
    const float* b_a     = (const float*)d_in[5];
    const float* Wih_r   = (const float*)d_in[6];
    const float* Whh_r   = (const float*)d_in[7];
    const float* b_r     = (const float*)d_in[8];
    const float* Wih_t   = (const float*)d_in[9];
    const float* Whh_t   = (const float*)d_in[10];
    const float* b_t     = (const float*)d_in[11];
    const float* e2act_w = (const float*)d_in[12];
    const float* e2act_b = (const float*)d_in[13];
    const float* e2res_w = (const float*)d_in[14];
    const float* e2res_b = (const float*)d_in[15];
    const float* e2ts_w1 = (const float*)d_in[16];
    const float* e2ts_b1 = (const float*)d_in[17];
    const float* e2ts_w2 = (const float*)d_in[18];
    const float* e2ts_b2 = (const float*)d_in[19];

    float* out_acts = (float*)d_out;                     // [1024][64][64]
    float* out_ts   = out_acts + (size_t)1024 * 64 * 64; // [1024][64]
    float* out_res  = out_ts + 1024 * 64;                // [1024][64][128]

    float* ws = (float*)d_ws;
    size_t off = 0;
    auto alloc = [&](size_t n) { float* p = ws + off; off += n; return p; };
    float* t_rec  = alloc((size_t)1024 * 512);
    float* base_a = alloc((size_t)1024 * 4096);
    float* base_r = alloc((size_t)1024 * 4096);
    float* base_t = alloc((size_t)1024 * 4096);
    float* Ea     = alloc((size_t)64 * 4096);
    float* Er_a   = alloc((size_t)64 * 4096);
    float* Er_r   = alloc((size_t)128 * 4096);
    float* Et_a   = alloc((size_t)64 * 4096);
    float* wtts   = alloc(4096);
    float* hc     = alloc((size_t)6 * 1024 * 1024);
    float* ha = hc, * ca = hc + 1048576, * hr = hc + 2097152;
    float* cr = hc + 3145728, * ht = hc + 4194304, * ct = hc + 5242880;
    float* gates0 = alloc((size_t)1024 * 4096);
    float* gates1 = alloc((size_t)1024 * 4096);
    float* part   = alloc((size_t)4 * 1024 * 512);  // shared act/res/ts partials (disjoint in time)
    float* u      = alloc((size_t)1024 * 512);
    float* tsv    = alloc(1024);
    int*   aidx   = (int*)alloc(1024);
    int*   ridx   = (int*)alloc(1024);

    dim3 blk(256);
    init_state<<<(6 * 1024 * 1024 + 255) / 256, blk, 0, stream>>>(hc, tsv, aidx, ridx, 6 * 1024 * 1024);

    // t_rec = relu(z @ z2t_w.T + z2t_b)   [1024,512]
    gemm_f32<<<dim3(8, 8, 1), blk, 0, stream>>>(z, z2t_w, t_rec, z, z2t_w, t_rec,
                                                256, 256, 512, 256, z2t_b, 1);
    // base_* = t_rec @ Wih_*[:, :512].T + b_*   [1024,4096]
    gemm_f32<<<dim3(8, 64, 1), blk, 0, stream>>>(t_rec, Wih_a, base_a, t_rec, Wih_a, base_a,
                                                 512, 576, 4096, 512, b_a, 0);
    gemm_f32<<<dim3(8, 64, 1), blk, 0, stream>>>(t_rec, Wih_r, base_r, t_rec, Wih_r, base_r,
                                                 512, 704, 4096, 512, b_r, 0);
    gemm_f32<<<dim3(8, 64, 1), blk, 0, stream>>>(t_rec, Wih_t, base_t, t_rec, Wih_t, base_t,
                                                 512, 577, 4096, 512, b_t, 0);
    // one-hot column tables
    extract_cols<<<(64 * 4096 + 255) / 256, blk, 0, stream>>>(Wih_a, 576, 512, 64, Ea);
    extract_cols<<<(64 * 4096 + 255) / 256, blk, 0, stream>>>(Wih_r, 704, 512, 64, Er_a);
    extract_cols<<<(128 * 4096 + 255) / 256, blk, 0, stream>>>(Wih_r, 704, 576, 128, Er_r);
    extract_cols<<<(64 * 4096 + 255) / 256, blk, 0, stream>>>(Wih_t, 577, 512, 64, Et_a);
    extract_cols<<<(4096 + 255) / 256, blk, 0, stream>>>(Wih_t, 577, 576, 1, wtts);

    for (int t = 0; t < 64; t++) {
        // stage a: gates = ha @ Whh_a.T ; pw uses previous act_idx
        gemm_f32<<<dim3(8, 64, 1), blk, 0, stream>>>(ha, Whh_a, gates0, ha, Whh_a, gates0,
                                                     1024, 1024, 4096, 1024, nullptr, 0);
        lstm_pw<<<4096, blk, 0, stream>>>(gates0, base_a, Ea, aidx, nullptr, nullptr,
                                          nullptr, nullptr, ha, ca);
        head_partial<64, 2, 8><<<dim3(16, 1, 8), blk, 0, stream>>>(ha, 1024, e2act_w, 1024,
                                                                   part, 64, 128);
        act_reduce<<<256, blk, 0, stream>>>(part, e2act_b, out_acts, t, aidx);
        // stages r & t: both depend only on new act_idx + their own h (batched via grid z)
        gemm_f32<<<dim3(8, 64, 2), blk, 0, stream>>>(hr, Whh_r, gates0, ht, Whh_t, gates1,
                                                     1024, 1024, 4096, 1024, nullptr, 0);
        lstm_pw<<<4096, blk, 0, stream>>>(gates0, base_r, Er_a, aidx, Er_r, ridx,
                                          nullptr, nullptr, hr, cr);
        lstm_pw<<<4096, blk, 0, stream>>>(gates1, base_t, Et_a, aidx, nullptr, nullptr,
                                          wtts, tsv, ht, ct);
        head_partial<128, 4, 8><<<dim3(16, 1, 8), blk, 0, stream>>>(hr, 1024, e2res_w, 1024,
                                                                    part, 128, 128);
        res_reduce<<<256, blk, 0, stream>>>(part, e2res_b, out_res, t, ridx);
        head_partial<64, 2, 8><<<dim3(16, 8, 4), blk, 0, stream>>>(ht, 1024, e2ts_w1, 1024,
                                                                   part, 512, 256);
        ts_u_kernel<<<2048, blk, 0, stream>>>(part, e2ts_b1, u);
        ts_final<<<256, blk, 0, stream>>>(u, e2ts_w2, e2ts_b2, out_ts, t, tsv);
    }
}

// Round 4
// 19852.615 us; speedup vs baseline: 1.4685x; 1.4685x over previous
//
#include <hip/hip_runtime.h>
#include <math.h>

// Decoder: B=1024, Z=256, TDIM=512, CF=1024, A=64, R=128, T=64
// R4: fp16 2-way-split MFMA GEMMs (3 terms, dual accumulators, lo scaled by 2^11).
//   x = hi + lo/2048 (fp16 each, representation err ~2^-22 ~ fp32)
//   C = Ah@Wh + (Al@Wh + Ah@Wl)/2048   (dropped lo*lo ~ 2^-22 rel)
//   R2/R3 bit-identical failures proved an act-argmax flip in the 3-term bf16 a-chain
//   (~1e-5 logit error); fp16 splits give ~5e-7 gate error = fp32-reorder level (R1 passed).

__device__ __forceinline__ float sigf(float x) { return 1.0f / (1.0f + expf(-x)); }

typedef __attribute__((ext_vector_type(8))) _Float16 f16x8;
typedef __attribute__((ext_vector_type(4))) float f32x4;

__device__ __forceinline__ void split_f16(float x, unsigned short& hi, unsigned short& lo) {
    _Float16 h = (_Float16)x;                   // RNE f32->f16
    float r = (x - (float)h) * 2048.0f;         // exact (Sterbenz + pow2 scale)
    _Float16 l = (_Float16)r;                   // RNE; normal range (scaled)
    hi = __builtin_bit_cast(unsigned short, h);
    lo = __builtin_bit_cast(unsigned short, l);
}

// ---------------- fp16-split MFMA GEMM: C = A[M,K] @ W[N,K]^T ----------------
// 128x128 tile, BK=32, 256 threads = 4 waves (2x2), each wave 64x64 (4x4 frags of 16x16).
struct SPH {
    const unsigned short* Ah; const unsigned short* Al;
    const unsigned short* Wh; const unsigned short* Wl;
    float* C;
};

__global__ __launch_bounds__(256) void gemm_f16s(
    SPH p0, SPH p1, int K, int N, const float* __restrict__ bias, int relu)
{
    SPH P = blockIdx.z ? p1 : p0;
    __shared__ unsigned short lds[16384];   // 32KB: Ah[0:4096) Al[4096) Wh[8192) Wl[12288)
    const int tid = threadIdx.x;
    const int wave = tid >> 6, lane = tid & 63;
    const int wm = wave >> 1, wn = wave & 1;
    const int lrow = lane & 15, lq = lane >> 4;
    const int m0 = blockIdx.x * 128, n0 = blockIdx.y * 128;

    f32x4 acch[4][4], accl[4][4];
#pragma unroll
    for (int i = 0; i < 4; i++)
#pragma unroll
        for (int j = 0; j < 4; j++) {
            acch[i][j] = (f32x4){0.f, 0.f, 0.f, 0.f};
            accl[i][j] = (f32x4){0.f, 0.f, 0.f, 0.f};
        }

    for (int k0 = 0; k0 < K; k0 += 32) {
        __syncthreads();
#pragma unroll
        for (int ss = 0; ss < 2; ss++) {
            int s = wave * 2 + ss;
            int mrow = m0 + s * 16 + lrow;
            int nrow = n0 + s * 16 + lrow;
            int k = k0 + lq * 8;
            __builtin_amdgcn_global_load_lds(
                (const __attribute__((address_space(1))) void*)(P.Ah + (size_t)mrow * K + k),
                (__attribute__((address_space(3))) void*)&lds[s * 512], 16, 0, 0);
            __builtin_amdgcn_global_load_lds(
                (const __attribute__((address_space(1))) void*)(P.Al + (size_t)mrow * K + k),
                (__attribute__((address_space(3))) void*)&lds[4096 + s * 512], 16, 0, 0);
            __builtin_amdgcn_global_load_lds(
                (const __attribute__((address_space(1))) void*)(P.Wh + (size_t)nrow * K + k),
                (__attribute__((address_space(3))) void*)&lds[8192 + s * 512], 16, 0, 0);
            __builtin_amdgcn_global_load_lds(
                (const __attribute__((address_space(1))) void*)(P.Wl + (size_t)nrow * K + k),
                (__attribute__((address_space(3))) void*)&lds[12288 + s * 512], 16, 0, 0);
        }
        __syncthreads();

        f16x8 ah[4], al[4], bh[4], bl[4];
#pragma unroll
        for (int mi = 0; mi < 4; mi++) {
            ah[mi] = *(const f16x8*)&lds[(wm * 4 + mi) * 512 + lane * 8];
            al[mi] = *(const f16x8*)&lds[4096 + (wm * 4 + mi) * 512 + lane * 8];
        }
#pragma unroll
        for (int ni = 0; ni < 4; ni++) {
            bh[ni] = *(const f16x8*)&lds[8192 + (wn * 4 + ni) * 512 + lane * 8];
            bl[ni] = *(const f16x8*)&lds[12288 + (wn * 4 + ni) * 512 + lane * 8];
        }
#pragma unroll
        for (int mi = 0; mi < 4; mi++)
#pragma unroll
            for (int ni = 0; ni < 4; ni++) {
                acch[mi][ni] = __builtin_amdgcn_mfma_f32_16x16x32_f16(ah[mi], bh[ni], acch[mi][ni], 0, 0, 0);
                accl[mi][ni] = __builtin_amdgcn_mfma_f32_16x16x32_f16(al[mi], bh[ni], accl[mi][ni], 0, 0, 0);
                accl[mi][ni] = __builtin_amdgcn_mfma_f32_16x16x32_f16(ah[mi], bl[ni], accl[mi][ni], 0, 0, 0);
            }
    }

    const float s_lo = 1.0f / 2048.0f;
#pragma unroll
    for (int mi = 0; mi < 4; mi++)
#pragma unroll
        for (int ni = 0; ni < 4; ni++) {
            int row = m0 + wm * 64 + mi * 16 + lq * 4;
            int col = n0 + wn * 64 + ni * 16 + lrow;
            float bv = bias ? bias[col] : 0.0f;
#pragma unroll
            for (int r = 0; r < 4; r++) {
                float v = acch[mi][ni][r] + accl[mi][ni][r] * s_lo + bv;
                if (relu) v = fmaxf(v, 0.0f);
                P.C[(size_t)(row + r) * N + col] = v;
            }
        }
}

// ---------------- fp32 GEMM (setup only) ----------------
__global__ __launch_bounds__(256) void gemm_f32(
    const float* __restrict__ A0, const float* __restrict__ W0, float* __restrict__ C0,
    const float* __restrict__ A1, const float* __restrict__ W1, float* __restrict__ C1,
    int lda, int ldw, int ldc, int K, const float* __restrict__ bias, int relu)
{
    const float* Ap = blockIdx.z ? A1 : A0;
    const float* Wp = blockIdx.z ? W1 : W0;
    float*       Cp = blockIdx.z ? C1 : C0;
    __shared__ float As[16][128];
    __shared__ float Bs[16][64];
    const int tid = threadIdx.x;
    const int m0 = blockIdx.x * 128, n0 = blockIdx.y * 64;
    const int tx = tid & 7, ty = tid >> 3;
    const bool wal = (ldw & 3) == 0;
    float acc[4][8];
#pragma unroll
    for (int i = 0; i < 4; i++)
#pragma unroll
        for (int j = 0; j < 8; j++) acc[i][j] = 0.0f;

    for (int k0 = 0; k0 < K; k0 += 16) {
        __syncthreads();
#pragma unroll
        for (int q = 0; q < 2; q++) {
            int t2 = tid + q * 256;
            int kq = t2 & 3, m = t2 >> 2;
            float4 v = *(const float4*)(Ap + (size_t)(m0 + m) * lda + k0 + kq * 4);
            As[kq * 4 + 0][m] = v.x; As[kq * 4 + 1][m] = v.y;
            As[kq * 4 + 2][m] = v.z; As[kq * 4 + 3][m] = v.w;
        }
        {
            int kq = tid & 3, n = tid >> 2;
            const float* src = Wp + (size_t)(n0 + n) * ldw + k0 + kq * 4;
            float4 v;
            if (wal) v = *(const float4*)src;
            else { v.x = src[0]; v.y = src[1]; v.z = src[2]; v.w = src[3]; }
            Bs[kq * 4 + 0][n] = v.x; Bs[kq * 4 + 1][n] = v.y;
            Bs[kq * 4 + 2][n] = v.z; Bs[kq * 4 + 3][n] = v.w;
        }
        __syncthreads();
#pragma unroll
        for (int k = 0; k < 16; k++) {
            float a4[4], b8[8];
            *(float4*)a4 = *(const float4*)&As[k][ty * 4];
            *(float4*)(b8) = *(const float4*)&Bs[k][tx * 8];
            *(float4*)(b8 + 4) = *(const float4*)&Bs[k][tx * 8 + 4];
#pragma unroll
            for (int i = 0; i < 4; i++)
#pragma unroll
                for (int j = 0; j < 8; j++) acc[i][j] = fmaf(a4[i], b8[j], acc[i][j]);
        }
    }
#pragma unroll
    for (int i = 0; i < 4; i++) {
        int m = m0 + ty * 4 + i;
        float vb[8];
#pragma unroll
        for (int j = 0; j < 8; j++) {
            float v = acc[i][j];
            if (bias) v += bias[n0 + tx * 8 + j];
            if (relu) v = fmaxf(v, 0.0f);
            vb[j] = v;
        }
        float* dst = Cp + (size_t)m * ldc + n0 + tx * 8;
        *(float4*)dst = make_float4(vb[0], vb[1], vb[2], vb[3]);
        *(float4*)(dst + 4) = make_float4(vb[4], vb[5], vb[6], vb[7]);
    }
}

// ------------- K-split small-N GEMM (act/res heads, fp32) -------------
template <int BN, int TM, int TN>
__global__ __launch_bounds__(256) void head_partial(
    const float* __restrict__ A, int lda,
    const float* __restrict__ W, int ldw,
    float* __restrict__ part, int N, int Kchunk)
{
    __shared__ float As[32][64];
    __shared__ float Bs[32][BN];
    const int tid = threadIdx.x;
    const int m0 = blockIdx.x * 64, n0 = blockIdx.y * BN;
    const int kc = blockIdx.z;
    constexpr int TX = BN / TN;
    const int tx = tid % TX, ty = tid / TX;
    float acc[TM][TN];
#pragma unroll
    for (int i = 0; i < TM; i++)
#pragma unroll
        for (int j = 0; j < TN; j++) acc[i][j] = 0.0f;

    const int kb = kc * Kchunk;
    for (int k0 = kb; k0 < kb + Kchunk; k0 += 32) {
        __syncthreads();
#pragma unroll
        for (int q = 0; q < 2; q++) {
            int t2 = tid + q * 256;
            int kq = t2 & 7, m = t2 >> 3;
            float4 v = *(const float4*)(A + (size_t)(m0 + m) * lda + k0 + kq * 4);
            As[kq * 4 + 0][m] = v.x; As[kq * 4 + 1][m] = v.y;
            As[kq * 4 + 2][m] = v.z; As[kq * 4 + 3][m] = v.w;
        }
#pragma unroll
        for (int q = 0; q < BN / 32; q++) {
            int t2 = tid + q * 256;
            int kq = t2 & 7, n = t2 >> 3;
            float4 v = *(const float4*)(W + (size_t)(n0 + n) * ldw + k0 + kq * 4);
            Bs[kq * 4 + 0][n] = v.x; Bs[kq * 4 + 1][n] = v.y;
            Bs[kq * 4 + 2][n] = v.z; Bs[kq * 4 + 3][n] = v.w;
        }
        __syncthreads();
#pragma unroll
        for (int k = 0; k < 32; k++) {
            float av[TM], bv[TN];
#pragma unroll
            for (int i = 0; i < TM; i++) av[i] = As[k][ty * TM + i];
#pragma unroll
            for (int j = 0; j < TN; j++) bv[j] = Bs[k][tx * TN + j];
#pragma unroll
            for (int i = 0; i < TM; i++)
#pragma unroll
                for (int j = 0; j < TN; j++) acc[i][j] = fmaf(av[i], bv[j], acc[i][j]);
        }
    }
#pragma unroll
    for (int i = 0; i < TM; i++) {
        int m = m0 + ty * TM + i;
        float* dst = part + ((size_t)kc * 1024 + m) * N + n0 + tx * TN;
#pragma unroll
        for (int j = 0; j < TN; j += 4)
            *(float4*)(dst + j) = make_float4(acc[i][j], acc[i][j + 1], acc[i][j + 2], acc[i][j + 3]);
    }
}

// ------------- pointwise LSTM (cell a) -------------
__global__ __launch_bounds__(256) void lstm_pw_a(
    const float* __restrict__ gates, const float* __restrict__ base,
    const float* __restrict__ E1, const int* __restrict__ idx1,
    float* __restrict__ h, float* __restrict__ c,
    unsigned short* __restrict__ h_hi, unsigned short* __restrict__ h_lo)
{
    int i = blockIdx.x * 256 + threadIdx.x;
    int b = i >> 10, j = i & 1023;
    size_t r = (size_t)b * 4096 + j;
    const float* e1 = E1 + (size_t)idx1[b] * 4096 + j;
    float gi = gates[r]        + base[r]        + e1[0];
    float gf = gates[r + 1024] + base[r + 1024] + e1[1024];
    float gg = gates[r + 2048] + base[r + 2048] + e1[2048];
    float go = gates[r + 3072] + base[r + 3072] + e1[3072];
    float cn = sigf(gf) * c[i] + sigf(gi) * tanhf(gg);
    c[i] = cn;
    float hn = sigf(go) * tanhf(cn);
    h[i] = hn;
    split_f16(hn, h_hi[i], h_lo[i]);
}

// ------------- fused pointwise LSTM for cells r and t -------------
__global__ __launch_bounds__(256) void lstm_pw_rt(
    const float* __restrict__ gates_r, const float* __restrict__ base_r,
    const float* __restrict__ Er_a, const float* __restrict__ Er_r,
    const int* __restrict__ aidx, const int* __restrict__ ridx,
    float* __restrict__ hr, float* __restrict__ cr,
    unsigned short* __restrict__ hr0, unsigned short* __restrict__ hr1,
    const float* __restrict__ gates_t, const float* __restrict__ base_t,
    const float* __restrict__ Et_a, const float* __restrict__ wtts, const float* __restrict__ tsv,
    float* __restrict__ ht, float* __restrict__ ct,
    unsigned short* __restrict__ ht0, unsigned short* __restrict__ ht1)
{
    int blk = blockIdx.x;
    int i = (blk & 4095) * 256 + threadIdx.x;
    int b = i >> 10, j = i & 1023;
    size_t r = (size_t)b * 4096 + j;
    if (blk < 4096) {
        const float* e1 = Er_a + (size_t)aidx[b] * 4096 + j;
        const float* e2 = Er_r + (size_t)ridx[b] * 4096 + j;
        float gi = gates_r[r]        + base_r[r]        + e1[0]    + e2[0];
        float gf = gates_r[r + 1024] + base_r[r + 1024] + e1[1024] + e2[1024];
        float gg = gates_r[r + 2048] + base_r[r + 2048] + e1[2048] + e2[2048];
        float go = gates_r[r + 3072] + base_r[r + 3072] + e1[3072] + e2[3072];
        float cn = sigf(gf) * cr[i] + sigf(gi) * tanhf(gg);
        cr[i] = cn;
        float hn = sigf(go) * tanhf(cn);
        hr[i] = hn;
        split_f16(hn, hr0[i], hr1[i]);
    } else {
        const float* e1 = Et_a + (size_t)aidx[b] * 4096 + j;
        float tv = tsv[b];
        float gi = gates_t[r]        + base_t[r]        + e1[0];
        float gf = gates_t[r + 1024] + base_t[r + 1024] + e1[1024];
        float gg = gates_t[r + 2048] + base_t[r + 2048] + e1[2048];
        float go = gates_t[r + 3072] + base_t[r + 3072] + e1[3072];
        gi = fmaf(tv, wtts[j], gi);        gf = fmaf(tv, wtts[j + 1024], gf);
        gg = fmaf(tv, wtts[j + 2048], gg); go = fmaf(tv, wtts[j + 3072], go);
        float cn = sigf(gf) * ct[i] + sigf(gi) * tanhf(gg);
        ct[i] = cn;
        float hn = sigf(go) * tanhf(cn);
        ht[i] = hn;
        split_f16(hn, ht0[i], ht1[i]);
    }
}

// ------------- act head reduce -------------
__global__ __launch_bounds__(256) void act_reduce(
    const float* __restrict__ part, const float* __restrict__ bias,
    float* __restrict__ out_probs, int t, int* __restrict__ aidx)
{
    int lane = threadIdx.x & 63;
    int b = blockIdx.x * 4 + (threadIdx.x >> 6);
    float l = bias[lane];
#pragma unroll
    for (int kc = 0; kc < 8; kc++) l += part[((size_t)kc * 1024 + b) * 64 + lane];
    float v = l; int idx = lane;
#pragma unroll
    for (int off = 32; off; off >>= 1) {
        float ov = __shfl_xor(v, off);
        int   oi = __shfl_xor(idx, off);
        if (ov > v || (ov == v && oi < idx)) { v = ov; idx = oi; }
    }
    float e = expf(l - v);
    float s = e;
#pragma unroll
    for (int off = 32; off; off >>= 1) s += __shfl_xor(s, off);
    out_probs[((size_t)b * 64 + t) * 64 + lane] = e / s;
    if (lane == 0) aidx[b] = idx;
}

__global__ __launch_bounds__(256) void res_reduce(
    const float* __restrict__ part, const float* __restrict__ bias,
    float* __restrict__ out_probs, int t, int* __restrict__ ridx)
{
    int lane = threadIdx.x & 63;
    int b = blockIdx.x * 4 + (threadIdx.x >> 6);
    float l0 = bias[lane], l1 = bias[lane + 64];
#pragma unroll
    for (int kc = 0; kc < 8; kc++) {
        const float* p = part + ((size_t)kc * 1024 + b) * 128;
        l0 += p[lane]; l1 += p[lane + 64];
    }
    float v = l0; int idx = lane;
    if (l1 > v) { v = l1; idx = lane + 64; }
#pragma unroll
    for (int off = 32; off; off >>= 1) {
        float ov = __shfl_xor(v, off);
        int   oi = __shfl_xor(idx, off);
        if (ov > v || (ov == v && oi < idx)) { v = ov; idx = oi; }
    }
    float e0 = expf(l0 - v), e1 = expf(l1 - v);
    float s = e0 + e1;
#pragma unroll
    for (int off = 32; off; off >>= 1) s += __shfl_xor(s, off);
    float* dst = out_probs + ((size_t)b * 64 + t) * 128;
    dst[lane] = e0 / s; dst[lane + 64] = e1 / s;
    if (lane == 0) ridx[b] = idx;
}

// ------------- ts final -------------
__global__ __launch_bounds__(256) void ts_final(
    const float* __restrict__ u, const float* __restrict__ w2, const float* __restrict__ b2,
    float* __restrict__ out_ts, int t, float* __restrict__ tsv)
{
    int lane = threadIdx.x & 63;
    int b = blockIdx.x * 4 + (threadIdx.x >> 6);
    const float* ur = u + (size_t)b * 512;
    float s = 0.0f;
#pragma unroll
    for (int q = 0; q < 8; q++) s = fmaf(ur[lane + q * 64], w2[lane + q * 64], s);
#pragma unroll
    for (int off = 32; off; off >>= 1) s += __shfl_xor(s, off);
    if (lane == 0) {
        float r = s + b2[0];
        out_ts[b * 64 + t] = r;
        tsv[b] = r;
    }
}

// ------------- setup kernels -------------
__global__ void extract_cols(const float* __restrict__ Wih, int ldw, int col0, int ncols,
                             float* __restrict__ E)
{
    int i = blockIdx.x * 256 + threadIdx.x;
    if (i >= ncols * 4096) return;
    int c = i % ncols, j = i / ncols;
    E[(size_t)c * 4096 + j] = Wih[(size_t)j * ldw + col0 + c];
}

__global__ void split_mat_h(const float* __restrict__ X,
                            unsigned short* __restrict__ hi, unsigned short* __restrict__ lo, int n)
{
    int i = blockIdx.x * 256 + threadIdx.x;
    if (i >= n) return;
    split_f16(X[i], hi[i], lo[i]);
}

__global__ void init_state(float* __restrict__ hc, unsigned int* __restrict__ hilo,
                           float* __restrict__ tsv, int* __restrict__ aidx, int* __restrict__ ridx)
{
    int i = blockIdx.x * 256 + threadIdx.x;
    if (i < 6 * 1024 * 1024) hc[i] = 0.0f;
    if (i < 3 * 1024 * 1024) hilo[i] = 0u;          // 6M ushort of split state
    if (i < 1024) { tsv[i] = 0.0f; aidx[i] = 63; ridx[i] = 127; }
}

extern "C" void kernel_launch(void* const* d_in, const int* in_sizes, int n_in,
                              void* d_out, int out_size, void* d_ws, size_t ws_size,
                              hipStream_t stream)
{
    const float* z       = (const float*)d_in[0];
    const float* z2t_w   = (const float*)d_in[1];
    const float* z2t_b   = (const float*)d_in[2];
    const float* Wih_a   = (const float*)d_in[3];
    const float* Whh_a   = (const float*)d_in[4];
    const float* b_a     = (const float*)d_in[5];
    const float* Wih_r   = (const float*)d_in[6];
    const float* Whh_r   = (const float*)d_in[7];
    const float* b_r     = (const float*)d_in[8];
    const float* Wih_t   = (const float*)d_in[9];
    const float* Whh_t   = (const float*)d_in[10];
    const float* b_t     = (const float*)d_in[11];
    const float* e2act_w = (const float*)d_in[12];
    const float* e2act_b = (const float*)d_in[13];
    const float* e2res_w = (const float*)d_in[14];
    const float* e2res_b = (const float*)d_in[15];
    const float* e2ts_w1 = (const float*)d_in[16];
    const float* e2ts_b1 = (const float*)d_in[17];
    const float* e2ts_w2 = (const float*)d_in[18];
    const float* e2ts_b2 = (const float*)d_in[19];

    float* out_acts = (float*)d_out;                     // [1024][64][64]
    float* out_ts   = out_acts + (size_t)1024 * 64 * 64; // [1024][64]
    float* out_res  = out_ts + 1024 * 64;                // [1024][64][128]

    float* ws = (float*)d_ws;
    size_t off = 0;
    auto alloc = [&](size_t n) { float* p = ws + off; off += n; return p; };
    float* t_rec  = alloc((size_t)1024 * 512);
    float* base_a = alloc((size_t)1024 * 4096);
    float* base_r = alloc((size_t)1024 * 4096);
    float* base_t = alloc((size_t)1024 * 4096);
    float* Ea     = alloc((size_t)64 * 4096);
    float* Er_a   = alloc((size_t)64 * 4096);
    float* Er_r   = alloc((size_t)128 * 4096);
    float* Et_a   = alloc((size_t)64 * 4096);
    float* wtts   = alloc(4096);
    float* hc     = alloc((size_t)6 * 1024 * 1024);
    float* ha = hc, * ca = hc + 1048576, * hr = hc + 2097152;
    float* cr = hc + 3145728, * ht = hc + 4194304, * ct = hc + 5242880;
    float* gates0 = alloc((size_t)1024 * 4096);
    float* gates1 = alloc((size_t)1024 * 4096);
    float* part   = alloc((size_t)4 * 1024 * 512);
    float* u      = alloc((size_t)1024 * 512);
    float* tsv    = alloc(1024);
    int*   aidx   = (int*)alloc(1024);
    int*   ridx   = (int*)alloc(1024);
    // split state: 6 arrays of 1M ushort = 3M floats
    unsigned short* hilo = (unsigned short*)alloc((size_t)3 * 1024 * 1024);
    const size_t U = 1048576;
    unsigned short* ha0 = hilo,         * ha1 = hilo + U;
    unsigned short* hr0 = hilo + 2 * U, * hr1 = hilo + 3 * U;
    unsigned short* ht0 = hilo + 4 * U, * ht1 = hilo + 5 * U;
    // split weights
    unsigned short* WA0 = (unsigned short*)alloc((size_t)2 * 1024 * 1024);
    unsigned short* WA1 = (unsigned short*)alloc((size_t)2 * 1024 * 1024);
    unsigned short* WR0 = (unsigned short*)alloc((size_t)2 * 1024 * 1024);
    unsigned short* WR1 = (unsigned short*)alloc((size_t)2 * 1024 * 1024);
    unsigned short* WT0 = (unsigned short*)alloc((size_t)2 * 1024 * 1024);
    unsigned short* WT1 = (unsigned short*)alloc((size_t)2 * 1024 * 1024);
    unsigned short* W10 = (unsigned short*)alloc((size_t)256 * 1024);
    unsigned short* W11 = (unsigned short*)alloc((size_t)256 * 1024);

    dim3 blk(256);
    init_state<<<(6 * 1024 * 1024 + 255) / 256, blk, 0, stream>>>(hc, (unsigned int*)hilo, tsv, aidx, ridx);

    // t_rec = relu(z @ z2t_w.T + z2t_b)
    gemm_f32<<<dim3(8, 8, 1), blk, 0, stream>>>(z, z2t_w, t_rec, z, z2t_w, t_rec,
                                                256, 256, 512, 256, z2t_b, 1);
    // base_* = t_rec @ Wih_*[:, :512].T + b_*
    gemm_f32<<<dim3(8, 64, 1), blk, 0, stream>>>(t_rec, Wih_a, base_a, t_rec, Wih_a, base_a,
                                                 512, 576, 4096, 512, b_a, 0);
    gemm_f32<<<dim3(8, 64, 1), blk, 0, stream>>>(t_rec, Wih_r, base_r, t_rec, Wih_r, base_r,
                                                 512, 704, 4096, 512, b_r, 0);
    gemm_f32<<<dim3(8, 64, 1), blk, 0, stream>>>(t_rec, Wih_t, base_t, t_rec, Wih_t, base_t,
                                                 512, 577, 4096, 512, b_t, 0);
    // one-hot column tables
    extract_cols<<<(64 * 4096 + 255) / 256, blk, 0, stream>>>(Wih_a, 576, 512, 64, Ea);
    extract_cols<<<(64 * 4096 + 255) / 256, blk, 0, stream>>>(Wih_r, 704, 512, 64, Er_a);
    extract_cols<<<(128 * 4096 + 255) / 256, blk, 0, stream>>>(Wih_r, 704, 576, 128, Er_r);
    extract_cols<<<(64 * 4096 + 255) / 256, blk, 0, stream>>>(Wih_t, 577, 512, 64, Et_a);
    extract_cols<<<(4096 + 255) / 256, blk, 0, stream>>>(Wih_t, 577, 576, 1, wtts);
    // weight splits (fp16 hi/lo, lo scaled by 2^11)
    split_mat_h<<<(4194304 + 255) / 256, blk, 0, stream>>>(Whh_a, WA0, WA1, 4194304);
    split_mat_h<<<(4194304 + 255) / 256, blk, 0, stream>>>(Whh_r, WR0, WR1, 4194304);
    split_mat_h<<<(4194304 + 255) / 256, blk, 0, stream>>>(Whh_t, WT0, WT1, 4194304);
    split_mat_h<<<(524288 + 255) / 256, blk, 0, stream>>>(e2ts_w1, W10, W11, 524288);

    SPH pa = {ha0, ha1, WA0, WA1, gates0};
    SPH pr = {hr0, hr1, WR0, WR1, gates0};
    SPH pt = {ht0, ht1, WT0, WT1, gates1};
    SPH pu = {ht0, ht1, W10, W11, u};

    for (int t = 0; t < 64; t++) {
        // cell a: gates0 = ha @ Whh_a.T
        gemm_f16s<<<dim3(8, 32, 1), blk, 0, stream>>>(pa, pa, 1024, 4096, nullptr, 0);
        lstm_pw_a<<<4096, blk, 0, stream>>>(gates0, base_a, Ea, aidx, ha, ca, ha0, ha1);
        head_partial<64, 2, 8><<<dim3(16, 1, 8), blk, 0, stream>>>(ha, 1024, e2act_w, 1024,
                                                                   part, 64, 128);
        act_reduce<<<256, blk, 0, stream>>>(part, e2act_b, out_acts, t, aidx);
        // cells r & t batched
        gemm_f16s<<<dim3(8, 32, 2), blk, 0, stream>>>(pr, pt, 1024, 4096, nullptr, 0);
        lstm_pw_rt<<<8192, blk, 0, stream>>>(gates0, base_r, Er_a, Er_r, aidx, ridx,
                                             hr, cr, hr0, hr1,
                                             gates1, base_t, Et_a, wtts, tsv,
                                             ht, ct, ht0, ht1);
        head_partial<128, 4, 8><<<dim3(16, 1, 8), blk, 0, stream>>>(hr, 1024, e2res_w, 1024,
                                                                    part, 128, 128);
        res_reduce<<<256, blk, 0, stream>>>(part, e2res_b, out_res, t, ridx);
        // ts head: u = relu(ht @ e2ts_w1.T + b1)
        gemm_f16s<<<dim3(8, 4, 1), blk, 0, stream>>>(pu, pu, 1024, 512, e2ts_b1, 1);
        ts_final<<<256, blk, 0, stream>>>(u, e2ts_w2, e2ts_b2, out_ts, t, tsv);
    }
}